// Round 3
// baseline (100.516 us; speedup 1.0000x reference)
//
#include <hip/hip_runtime.h>
#include <hip/hip_cooperative_groups.h>
#include <hip/hip_bf16.h>

namespace cg = cooperative_groups;

#define H 1024
#define MAXLEN 512

__device__ __forceinline__ float wave_reduce_sum(float a) {
    #pragma unroll
    for (int off = 32; off; off >>= 1) a += __shfl_xor(a, off);
    return a;
}
__device__ __forceinline__ float wave_reduce_max(float a) {
    #pragma unroll
    for (int off = 32; off; off >>= 1) a = fmaxf(a, __shfl_xor(a, off));
    return a;
}

// ws layout (floats): logits[512] @ 0 | partial[4][1024] @ 512 | x[1024] @ 4608
__global__ void fused_decoder(const int* __restrict__ inputId,
                              const float* __restrict__ hidden,
                              const float* __restrict__ enc,
                              const float* __restrict__ embed_table,
                              const float* __restrict__ attn_w,
                              const float* __restrict__ attn_b,
                              const float* __restrict__ comb_w,
                              const float* __restrict__ comb_b,
                              const float* __restrict__ w_ih,
                              const float* __restrict__ b_ih,
                              const float* __restrict__ b_hh,
                              float* __restrict__ d_out,
                              float* __restrict__ ws) {
    cg::grid_group grid = cg::this_grid();

    __shared__ float w_lds[MAXLEN];
    __shared__ float red[4];
    __shared__ float part[8][32];

    const int tid  = threadIdx.x;           // 0..255
    const int lane = tid & 63;
    const int wid  = tid >> 6;               // 0..3
    const int gw   = blockIdx.x * 4 + wid;   // global wave id 0..1023

    float* logits  = ws;
    float* partial = ws + 512;               // [4][1024]
    float* x       = ws + 512 + 4096;        // [1024]

    const float* embed = embed_table + (size_t)inputId[0] * H;

    // ---------------- Phase A: logits[row] = attn_w[row,:] . [embed|hidden] + attn_b[row]
    if (gw < MAXLEN) {
        const float* wrow = attn_w + (size_t)gw * (2 * H);
        float acc = 0.f;
        #pragma unroll
        for (int it = 0; it < 8; ++it) {
            int base = it * 256 + lane * 4;
            float4 wv = *reinterpret_cast<const float4*>(wrow + base);
            float4 cv = (it < 4)
                ? *reinterpret_cast<const float4*>(embed + base)
                : *reinterpret_cast<const float4*>(hidden + (base - H));
            acc += wv.x * cv.x + wv.y * cv.y + wv.z * cv.z + wv.w * cv.w;
        }
        acc = wave_reduce_sum(acc);
        if (lane == 0) logits[gw] = acc + attn_b[gw];
    }

    grid.sync();

    // ---------------- Phase B: softmax (redundant per block) + partial apply.
    // Blocks 0..127: stripe = b>>2 (32 cols), k-range = b&3 (128 k's).
    if (blockIdx.x < 128) {
        float l0 = logits[tid];
        float l1 = logits[tid + 256];

        float m = wave_reduce_max(fmaxf(l0, l1));
        if (lane == 0) red[wid] = m;
        __syncthreads();
        m = fmaxf(fmaxf(red[0], red[1]), fmaxf(red[2], red[3]));
        __syncthreads();

        float e0 = expf(l0 - m), e1 = expf(l1 - m);
        float s = wave_reduce_sum(e0 + e1);
        if (lane == 0) red[wid] = s;
        __syncthreads();
        s = red[0] + red[1] + red[2] + red[3];
        float inv = 1.f / s;

        float w0 = e0 * inv, w1 = e1 * inv;
        w_lds[tid] = w0;
        w_lds[tid + 256] = w1;
        if (blockIdx.x == 0) {                  // attnWeights output
            d_out[2048 + tid] = w0;
            d_out[2048 + tid + 256] = w1;
        }
        __syncthreads();

        int c      = tid & 31;                  // col within stripe
        int ks     = tid >> 5;                  // k sub-slice 0..7
        int stripe = blockIdx.x >> 2;
        int kr     = blockIdx.x & 3;
        int col    = stripe * 32 + c;
        int k0     = kr * 128;
        float acc = 0.f;
        #pragma unroll
        for (int i = 0; i < 16; ++i) {
            int k = k0 + ks + i * 8;
            acc += w_lds[k] * enc[(size_t)k * H + col];
        }
        part[ks][c] = acc;
        __syncthreads();
        if (tid < 32) {
            float t = 0.f;
            #pragma unroll
            for (int i = 0; i < 8; ++i) t += part[i][tid];
            partial[kr * 1024 + stripe * 32 + tid] = t;
        }
    }

    grid.sync();

    // ---------------- Phase C: x[row] = relu(comb_w[row,:] . [embed|attnApplied] + comb_b[row])
    {
        const int row = gw;                     // 0..1023
        const float* wrow = comb_w + (size_t)row * (2 * H);
        float acc = 0.f;
        #pragma unroll
        for (int it = 0; it < 8; ++it) {
            int base = it * 256 + lane * 4;
            float4 wv = *reinterpret_cast<const float4*>(wrow + base);
            float4 cv;
            if (it < 4) {
                cv = *reinterpret_cast<const float4*>(embed + base);
            } else {
                int j = base - H;               // 0..1023
                float4 p0 = *reinterpret_cast<const float4*>(partial + j);
                float4 p1 = *reinterpret_cast<const float4*>(partial + 1024 + j);
                float4 p2 = *reinterpret_cast<const float4*>(partial + 2048 + j);
                float4 p3 = *reinterpret_cast<const float4*>(partial + 3072 + j);
                cv.x = p0.x + p1.x + p2.x + p3.x;
                cv.y = p0.y + p1.y + p2.y + p3.y;
                cv.z = p0.z + p1.z + p2.z + p3.z;
                cv.w = p0.w + p1.w + p2.w + p3.w;
            }
            acc += wv.x * cv.x + wv.y * cv.y + wv.z * cv.z + wv.w * cv.w;
        }
        acc = wave_reduce_sum(acc);
        if (lane == 0) x[row] = fmaxf(acc + comb_b[row], 0.f);
    }

    grid.sync();

    // ---------------- Phase D: GRU step (h0 = 0 -> gh = b_hh). One j per wave.
    {
        const int j = gw;                       // 0..1023
        float acc0 = 0.f, acc1 = 0.f, acc2 = 0.f;
        const float* wr = w_ih + (size_t)j * H;
        const float* wz = w_ih + (size_t)(H + j) * H;
        const float* wn = w_ih + (size_t)(2 * H + j) * H;
        #pragma unroll
        for (int it = 0; it < 4; ++it) {
            int base = it * 256 + lane * 4;
            float4 xv = *reinterpret_cast<const float4*>(x + base);
            float4 a = *reinterpret_cast<const float4*>(wr + base);
            float4 b = *reinterpret_cast<const float4*>(wz + base);
            float4 c = *reinterpret_cast<const float4*>(wn + base);
            acc0 += a.x * xv.x + a.y * xv.y + a.z * xv.z + a.w * xv.w;
            acc1 += b.x * xv.x + b.y * xv.y + b.z * xv.z + b.w * xv.w;
            acc2 += c.x * xv.x + c.y * xv.y + c.z * xv.z + c.w * xv.w;
        }
        #pragma unroll
        for (int off = 32; off; off >>= 1) {
            acc0 += __shfl_xor(acc0, off);
            acc1 += __shfl_xor(acc1, off);
            acc2 += __shfl_xor(acc2, off);
        }
        if (lane == 0) {
            float gi_r = acc0 + b_ih[j];
            float gi_z = acc1 + b_ih[H + j];
            float gi_n = acc2 + b_ih[2 * H + j];
            float r = 1.f / (1.f + expf(-(gi_r + b_hh[j])));
            float z = 1.f / (1.f + expf(-(gi_z + b_hh[H + j])));
            float n = tanhf(gi_n + r * b_hh[2 * H + j]);
            float hnew = (1.f - z) * n;         // + z*h0, h0 = 0
            float outv = 1.f / (1.f + expf(-hnew));
            d_out[j] = outv;                    // out
            d_out[H + j] = hnew;                // h_new
        }
    }
}

extern "C" void kernel_launch(void* const* d_in, const int* in_sizes, int n_in,
                              void* d_out, int out_size, void* d_ws, size_t ws_size,
                              hipStream_t stream) {
    const int*   inputId     = (const int*)d_in[0];
    const float* hidden      = (const float*)d_in[1];
    const float* enc         = (const float*)d_in[2];
    const float* embed_table = (const float*)d_in[3];
    const float* attn_w      = (const float*)d_in[4];
    const float* attn_b      = (const float*)d_in[5];
    const float* comb_w      = (const float*)d_in[6];
    const float* comb_b      = (const float*)d_in[7];
    const float* w_ih        = (const float*)d_in[8];
    // d_in[9] = w_hh is dead: h0 == 0 so gh = b_hh
    const float* b_ih        = (const float*)d_in[10];
    const float* b_hh        = (const float*)d_in[11];

    float* out = (float*)d_out;   // [0:1024) out, [1024:2048) h_new, [2048:2560) attnWeights
    float* ws  = (float*)d_ws;

    void* args[] = {
        (void*)&inputId, (void*)&hidden, (void*)&enc, (void*)&embed_table,
        (void*)&attn_w, (void*)&attn_b, (void*)&comb_w, (void*)&comb_b,
        (void*)&w_ih, (void*)&b_ih, (void*)&b_hh, (void*)&out, (void*)&ws
    };
    hipLaunchCooperativeKernel((const void*)fused_decoder, dim3(256), dim3(256),
                               args, 0, stream);
}

// Round 4
// 74.341 us; speedup vs baseline: 1.3521x; 1.3521x over previous
//
#include <hip/hip_runtime.h>
#include <hip/hip_bf16.h>

#define H 1024
#define MAXLEN 512
#define NB 256

__device__ __forceinline__ float wave_reduce_sum(float a) {
    #pragma unroll
    for (int off = 32; off; off >>= 1) a += __shfl_xor(a, off);
    return a;
}
__device__ __forceinline__ float wave_reduce_max(float a) {
    #pragma unroll
    for (int off = 32; off; off >>= 1) a = fmaxf(a, __shfl_xor(a, off));
    return a;
}

// Agent-scope coherent access (sc0/sc1): bypasses non-coherent per-XCD L2s,
// so cross-block data exchange needs NO cache writeback/invalidate.
__device__ __forceinline__ float cohLoad(const float* p) {
    return __hip_atomic_load(p, __ATOMIC_RELAXED, __HIP_MEMORY_SCOPE_AGENT);
}
__device__ __forceinline__ void cohStore(float* p, float v) {
    __hip_atomic_store(p, v, __ATOMIC_RELAXED, __HIP_MEMORY_SCOPE_AGENT);
}

// Lightweight grid barrier: monotone counter, no cache maintenance.
// (cg::grid.sync() costs ~27us/barrier on gfx950 due to L2 WB/INV — measured R3.)
__device__ __forceinline__ void gbar(unsigned* cnt, unsigned target) {
    __syncthreads();
    if (threadIdx.x == 0) {
        __hip_atomic_fetch_add(cnt, 1u, __ATOMIC_ACQ_REL, __HIP_MEMORY_SCOPE_AGENT);
        while (__hip_atomic_load(cnt, __ATOMIC_RELAXED, __HIP_MEMORY_SCOPE_AGENT) < target)
            __builtin_amdgcn_s_sleep(2);
        __builtin_amdgcn_fence(__ATOMIC_ACQUIRE, "agent");
    }
    __syncthreads();
}

// ws layout (floats, after 256-byte counter region):
//   logits[512] | y1[1024] | partial[4][1024] | x[1024]
__global__ void fused_decoder(const int* __restrict__ inputId,
                              const float* __restrict__ hidden,
                              const float* __restrict__ enc,
                              const float* __restrict__ embed_table,
                              const float* __restrict__ attn_w,
                              const float* __restrict__ attn_b,
                              const float* __restrict__ comb_w,
                              const float* __restrict__ comb_b,
                              const float* __restrict__ w_ih,
                              const float* __restrict__ b_ih,
                              const float* __restrict__ b_hh,
                              float* __restrict__ d_out,
                              float* __restrict__ wsraw) {
    unsigned* cnt = (unsigned*)wsraw;
    float* logits  = wsraw + 64;
    float* y1      = logits + 512;
    float* partial = y1 + 1024;        // [4][1024]
    float* x       = partial + 4096;   // [1024]

    __shared__ float w_sm[MAXLEN];
    __shared__ float red[4];
    __shared__ float part[16][16];
    __shared__ float vec_lds[H];       // a (phase C) then reused... separate names below

    const int tid  = threadIdx.x;
    const int lane = tid & 63;
    const int wid  = tid >> 6;          // 0..3
    const int b    = blockIdx.x;

    const float* embed = embed_table + (size_t)inputId[0] * H;

    // ---------------- Phase A ----------------
    // blocks 0..127: logits[row] = attn_w[row,:].[embed|hidden] + attn_b[row]
    // blocks 128..255: y1[row] = W1[row,:].embed + comb_b[row]   (W1 = comb_w[:, :1024])
    if (b < 128) {
        int row = b * 4 + wid;          // 0..511
        const float* wrow = attn_w + (size_t)row * (2 * H);
        float acc = 0.f;
        #pragma unroll
        for (int it = 0; it < 8; ++it) {
            int base = it * 256 + lane * 4;
            float4 wv = *reinterpret_cast<const float4*>(wrow + base);
            float4 cv = (it < 4)
                ? *reinterpret_cast<const float4*>(embed + base)
                : *reinterpret_cast<const float4*>(hidden + (base - H));
            acc += wv.x * cv.x + wv.y * cv.y + wv.z * cv.z + wv.w * cv.w;
        }
        acc = wave_reduce_sum(acc);
        if (lane == 0) cohStore(logits + row, acc + attn_b[row]);
    } else {
        int wv = (b - 128) * 4 + wid;   // 0..511
        #pragma unroll
        for (int rr = 0; rr < 2; ++rr) {
            int row = wv * 2 + rr;      // 0..1023
            const float* wrow = comb_w + (size_t)row * (2 * H);
            float acc = 0.f;
            #pragma unroll
            for (int it = 0; it < 4; ++it) {
                int base = it * 256 + lane * 4;
                float4 w4 = *reinterpret_cast<const float4*>(wrow + base);
                float4 e4 = *reinterpret_cast<const float4*>(embed + base);
                acc += w4.x * e4.x + w4.y * e4.y + w4.z * e4.z + w4.w * e4.w;
            }
            acc = wave_reduce_sum(acc);
            if (lane == 0) cohStore(y1 + row, acc + comb_b[row]);
        }
    }

    gbar(cnt, NB * 1);

    // ---------------- Phase B: softmax (redundant per block) + partial apply ----------------
    {
        float l0 = cohLoad(logits + tid);
        float l1 = cohLoad(logits + tid + 256);

        float m = wave_reduce_max(fmaxf(l0, l1));
        if (lane == 0) red[wid] = m;
        __syncthreads();
        m = fmaxf(fmaxf(red[0], red[1]), fmaxf(red[2], red[3]));
        __syncthreads();

        float e0 = expf(l0 - m), e1 = expf(l1 - m);
        float s = wave_reduce_sum(e0 + e1);
        if (lane == 0) red[wid] = s;
        __syncthreads();
        s = red[0] + red[1] + red[2] + red[3];
        float inv = 1.f / s;

        float w0 = e0 * inv, w1 = e1 * inv;
        w_sm[tid] = w0;
        w_sm[tid + 256] = w1;
        if (b == 0) {                   // attnWeights output
            d_out[2048 + tid] = w0;
            d_out[2048 + 256 + tid] = w1;
        }
        __syncthreads();

        // 256 blocks: stripe = b>>2 (64 stripes x 16 cols), kr = b&3 (128 k's)
        int c  = tid & 15;
        int ks = tid >> 4;              // 0..15
        int stripe = b >> 2;
        int kr = b & 3;
        int col = stripe * 16 + c;
        int k0 = kr * 128 + ks * 8;
        float acc = 0.f;
        #pragma unroll
        for (int i = 0; i < 8; ++i) {
            int k = k0 + i;
            acc += w_sm[k] * enc[(size_t)k * H + col];
        }
        part[ks][c] = acc;
        __syncthreads();
        if (tid < 16) {
            float t = 0.f;
            #pragma unroll
            for (int i = 0; i < 16; ++i) t += part[i][tid];
            cohStore(partial + kr * 1024 + stripe * 16 + tid, t);
        }
    }

    gbar(cnt, NB * 2);

    // ---------------- Phase C: x[row] = relu(y1[row] + W2[row,:].a) ----------------
    {
        // reduce partials into LDS a[1024] (shared by the block's 4 rows)
        for (int j = tid; j < H; j += 256) {
            float t = cohLoad(partial + j) + cohLoad(partial + 1024 + j)
                    + cohLoad(partial + 2048 + j) + cohLoad(partial + 3072 + j);
            vec_lds[j] = t;
        }
        __syncthreads();

        int row = b * 4 + wid;          // 0..1023
        const float* wrow = comb_w + (size_t)row * (2 * H) + H;  // W2 half
        float acc = 0.f;
        #pragma unroll
        for (int it = 0; it < 4; ++it) {
            int base = it * 256 + lane * 4;
            float4 w4 = *reinterpret_cast<const float4*>(wrow + base);
            float4 a4 = *reinterpret_cast<const float4*>(vec_lds + base);
            acc += w4.x * a4.x + w4.y * a4.y + w4.z * a4.z + w4.w * a4.w;
        }
        acc = wave_reduce_sum(acc);
        if (lane == 0) cohStore(x + row, fmaxf(cohLoad(y1 + row) + acc, 0.f));
    }

    gbar(cnt, NB * 3);

    // ---------------- Phase D: GRU (h0 = 0 -> gh = b_hh) ----------------
    {
        __syncthreads();                // vec_lds reuse
        for (int j = tid; j < H; j += 256) vec_lds[j] = cohLoad(x + j);
        __syncthreads();

        int j = b * 4 + wid;            // 0..1023
        float acc0 = 0.f, acc1 = 0.f, acc2 = 0.f;
        const float* wr = w_ih + (size_t)j * H;
        const float* wz = w_ih + (size_t)(H + j) * H;
        const float* wn = w_ih + (size_t)(2 * H + j) * H;
        #pragma unroll
        for (int it = 0; it < 4; ++it) {
            int base = it * 256 + lane * 4;
            float4 xv = *reinterpret_cast<const float4*>(vec_lds + base);
            float4 a4 = *reinterpret_cast<const float4*>(wr + base);
            float4 b4 = *reinterpret_cast<const float4*>(wz + base);
            float4 c4 = *reinterpret_cast<const float4*>(wn + base);
            acc0 += a4.x * xv.x + a4.y * xv.y + a4.z * xv.z + a4.w * xv.w;
            acc1 += b4.x * xv.x + b4.y * xv.y + b4.z * xv.z + b4.w * xv.w;
            acc2 += c4.x * xv.x + c4.y * xv.y + c4.z * xv.z + c4.w * xv.w;
        }
        #pragma unroll
        for (int off = 32; off; off >>= 1) {
            acc0 += __shfl_xor(acc0, off);
            acc1 += __shfl_xor(acc1, off);
            acc2 += __shfl_xor(acc2, off);
        }
        if (lane == 0) {
            float gi_r = acc0 + b_ih[j];
            float gi_z = acc1 + b_ih[H + j];
            float gi_n = acc2 + b_ih[2 * H + j];
            float r = 1.f / (1.f + expf(-(gi_r + b_hh[j])));
            float z = 1.f / (1.f + expf(-(gi_z + b_hh[H + j])));
            float n = tanhf(gi_n + r * b_hh[2 * H + j]);
            float hnew = (1.f - z) * n;     // + z*h0, h0 = 0
            float outv = 1.f / (1.f + expf(-hnew));
            d_out[j] = outv;                // out
            d_out[H + j] = hnew;            // h_new
        }
    }
}

extern "C" void kernel_launch(void* const* d_in, const int* in_sizes, int n_in,
                              void* d_out, int out_size, void* d_ws, size_t ws_size,
                              hipStream_t stream) {
    const int*   inputId     = (const int*)d_in[0];
    const float* hidden      = (const float*)d_in[1];
    const float* enc         = (const float*)d_in[2];
    const float* embed_table = (const float*)d_in[3];
    const float* attn_w      = (const float*)d_in[4];
    const float* attn_b      = (const float*)d_in[5];
    const float* comb_w      = (const float*)d_in[6];
    const float* comb_b      = (const float*)d_in[7];
    const float* w_ih        = (const float*)d_in[8];
    // d_in[9] = w_hh is dead: h0 == 0 so gh = b_hh
    const float* b_ih        = (const float*)d_in[10];
    const float* b_hh        = (const float*)d_in[11];

    float* out = (float*)d_out;   // [0:1024) out, [1024:2048) h_new, [2048:2560) attnWeights
    float* ws  = (float*)d_ws;

    // zero the barrier counter (graph-capturable async memset node)
    hipMemsetAsync(d_ws, 0, 256, stream);

    void* args[] = {
        (void*)&inputId, (void*)&hidden, (void*)&enc, (void*)&embed_table,
        (void*)&attn_w, (void*)&attn_b, (void*)&comb_w, (void*)&comb_b,
        (void*)&w_ih, (void*)&b_ih, (void*)&b_hh, (void*)&out, (void*)&ws
    };
    hipLaunchCooperativeKernel((const void*)fused_decoder, dim3(NB), dim3(256),
                               args, 0, stream);
}

// Round 5
// 54.330 us; speedup vs baseline: 1.8501x; 1.3683x over previous
//
#include <hip/hip_runtime.h>
#include <hip/hip_bf16.h>

#define H 1024
#define MAXLEN 512
#define NB 64      // blocks (CUs), 8 groups x 8
#define NT 512     // threads/block = 8 waves

__device__ __forceinline__ float wave_reduce_sum(float a) {
    #pragma unroll
    for (int off = 32; off; off >>= 1) a += __shfl_xor(a, off);
    return a;
}
__device__ __forceinline__ float wave_reduce_max(float a) {
    #pragma unroll
    for (int off = 32; off; off >>= 1) a = fmaxf(a, __shfl_xor(a, off));
    return a;
}

// Agent-scope coherent access (bypasses non-coherent per-XCD L2s) — proven R4.
__device__ __forceinline__ float cohLoad(const float* p) {
    return __hip_atomic_load(p, __ATOMIC_RELAXED, __HIP_MEMORY_SCOPE_AGENT);
}
__device__ __forceinline__ void cohStore(float* p, float v) {
    __hip_atomic_store(p, v, __ATOMIC_RELAXED, __HIP_MEMORY_SCOPE_AGENT);
}

// Two-level tree barrier: 8 group counters (own 128B lines) + 1 root line.
// Flat 256-RMW counter measured ~20us/barrier (R4); tree-8x8 should be ~2-3us.
__device__ __forceinline__ void gbar(unsigned* grpc, unsigned* root, int b, unsigned phase) {
    __syncthreads();
    if (threadIdx.x == 0) {
        unsigned g = (unsigned)b >> 3;                      // group 0..7
        unsigned old = __hip_atomic_fetch_add(grpc + g * 32, 1u,
                          __ATOMIC_ACQ_REL, __HIP_MEMORY_SCOPE_AGENT);
        if (old == phase * 8u - 1u)                         // last in group this phase
            __hip_atomic_fetch_add(root, 1u,
                          __ATOMIC_ACQ_REL, __HIP_MEMORY_SCOPE_AGENT);
        while (__hip_atomic_load(root, __ATOMIC_RELAXED, __HIP_MEMORY_SCOPE_AGENT)
                   < phase * 8u)
            __builtin_amdgcn_s_sleep(1);
        __builtin_amdgcn_fence(__ATOMIC_ACQUIRE, "agent");
    }
    __syncthreads();
}

// ws layout (floats):
//   [0..512)   barrier counters (grpc uints 0..255 stride 32, root uint 256)
//   [512..1024)  logits[512]
//   [1024..2048) y1[1024]        (= W1.embed + comb_b)
//   [2048..3072) avec[1024]      (= attnApplied)
//   [3072..4096) xvec[1024]
__global__ void fused_decoder(const int* __restrict__ inputId,
                              const float* __restrict__ hidden,
                              const float* __restrict__ enc,
                              const float* __restrict__ embed_table,
                              const float* __restrict__ attn_w,
                              const float* __restrict__ attn_b,
                              const float* __restrict__ comb_w,
                              const float* __restrict__ comb_b,
                              const float* __restrict__ w_ih,
                              const float* __restrict__ b_ih,
                              const float* __restrict__ b_hh,
                              float* __restrict__ d_out,
                              float* __restrict__ wsraw) {
    unsigned* grpc = (unsigned*)wsraw;
    unsigned* root = (unsigned*)wsraw + 256;
    float* logits = wsraw + 512;
    float* y1     = wsraw + 1024;
    float* avec   = wsraw + 2048;
    float* xvec   = wsraw + 3072;

    __shared__ float vec_lds[H];
    __shared__ float w_sm[MAXLEN];
    __shared__ float redm[8], reds[8];
    __shared__ float part[32][16];

    const int tid  = threadIdx.x;       // 0..511
    const int lane = tid & 63;
    const int w    = tid >> 6;          // wave 0..7
    const int b    = blockIdx.x;        // 0..63

    const float* embed = embed_table + (size_t)inputId[0] * H;

    // ---------------- Phase A: logits (1 row/wave) + y1 (2 rows/wave) ----------------
    {
        int row = b * 8 + w;            // 0..511
        const float* wrow = attn_w + (size_t)row * (2 * H);
        float acc = 0.f;
        #pragma unroll
        for (int it = 0; it < 8; ++it) {
            int base = it * 256 + lane * 4;
            float4 wv = *reinterpret_cast<const float4*>(wrow + base);
            float4 cv = (it < 4)
                ? *reinterpret_cast<const float4*>(embed + base)
                : *reinterpret_cast<const float4*>(hidden + (base - H));
            acc += wv.x * cv.x + wv.y * cv.y + wv.z * cv.z + wv.w * cv.w;
        }
        acc = wave_reduce_sum(acc);
        if (lane == 0) cohStore(logits + row, acc + attn_b[row]);

        #pragma unroll
        for (int rr = 0; rr < 2; ++rr) {
            int r2 = row * 2 + rr;      // 0..1023
            const float* w2 = comb_w + (size_t)r2 * (2 * H);
            float a2 = 0.f;
            #pragma unroll
            for (int it = 0; it < 4; ++it) {
                int base = it * 256 + lane * 4;
                float4 wv = *reinterpret_cast<const float4*>(w2 + base);
                float4 ev = *reinterpret_cast<const float4*>(embed + base);
                a2 += wv.x * ev.x + wv.y * ev.y + wv.z * ev.z + wv.w * ev.w;
            }
            a2 = wave_reduce_sum(a2);
            if (lane == 0) cohStore(y1 + r2, a2 + comb_b[r2]);
        }
    }
    gbar(grpc, root, b, 1);

    // ---------------- Phase B: softmax (redundant/block) + apply (16 cols/block) ----------------
    {
        float l = cohLoad(logits + tid);            // NT == MAXLEN
        float m = wave_reduce_max(l);
        if (lane == 0) redm[w] = m;
        __syncthreads();
        m = redm[0];
        #pragma unroll
        for (int i = 1; i < 8; ++i) m = fmaxf(m, redm[i]);
        float e = expf(l - m);
        float s = wave_reduce_sum(e);
        if (lane == 0) reds[w] = s;
        __syncthreads();
        s = 0.f;
        #pragma unroll
        for (int i = 0; i < 8; ++i) s += reds[i];
        float wgt = e / s;
        w_sm[tid] = wgt;
        if (b == 0) d_out[2048 + tid] = wgt;        // attnWeights
        __syncthreads();

        int c  = tid & 15;
        int ks = tid >> 4;                          // 0..31
        int col = b * 16 + c;
        float acc = 0.f;
        #pragma unroll
        for (int i = 0; i < 16; ++i) {
            int k = ks * 16 + i;
            acc += w_sm[k] * enc[(size_t)k * H + col];
        }
        part[ks][c] = acc;
        __syncthreads();
        if (tid < 16) {
            float t = 0.f;
            #pragma unroll
            for (int i = 0; i < 32; ++i) t += part[i][tid];
            cohStore(avec + b * 16 + tid, t);
        }
    }
    gbar(grpc, root, b, 2);

    // ---------------- Phase C: x = relu(y1 + W2 . a) ----------------
    {
        vec_lds[tid]       = cohLoad(avec + tid);
        vec_lds[tid + 512] = cohLoad(avec + tid + 512);
        __syncthreads();
        #pragma unroll
        for (int rr = 0; rr < 2; ++rr) {
            int row = (b * 8 + w) * 2 + rr;         // 0..1023
            const float* wrow = comb_w + (size_t)row * (2 * H) + H;   // W2 half
            float acc = 0.f;
            #pragma unroll
            for (int it = 0; it < 4; ++it) {
                int base = it * 256 + lane * 4;
                float4 wv = *reinterpret_cast<const float4*>(wrow + base);
                float4 av = *reinterpret_cast<const float4*>(vec_lds + base);
                acc += wv.x * av.x + wv.y * av.y + wv.z * av.z + wv.w * av.w;
            }
            acc = wave_reduce_sum(acc);
            if (lane == 0)
                cohStore(xvec + row, fmaxf(cohLoad(y1 + row) + acc, 0.f));
        }
    }
    gbar(grpc, root, b, 3);

    // ---------------- Phase D: GRU (h0 = 0 -> gh = b_hh) ----------------
    {
        // gbar ended with __syncthreads; all phase-C reads of vec_lds are done.
        vec_lds[tid]       = cohLoad(xvec + tid);
        vec_lds[tid + 512] = cohLoad(xvec + tid + 512);
        __syncthreads();
        #pragma unroll
        for (int rr = 0; rr < 2; ++rr) {
            int j = (b * 8 + w) * 2 + rr;           // 0..1023
            float acc0 = 0.f, acc1 = 0.f, acc2 = 0.f;
            const float* wr = w_ih + (size_t)j * H;
            const float* wz = w_ih + (size_t)(H + j) * H;
            const float* wn = w_ih + (size_t)(2 * H + j) * H;
            #pragma unroll
            for (int it = 0; it < 4; ++it) {
                int base = it * 256 + lane * 4;
                float4 xv = *reinterpret_cast<const float4*>(vec_lds + base);
                float4 a4 = *reinterpret_cast<const float4*>(wr + base);
                float4 b4 = *reinterpret_cast<const float4*>(wz + base);
                float4 c4 = *reinterpret_cast<const float4*>(wn + base);
                acc0 += a4.x * xv.x + a4.y * xv.y + a4.z * xv.z + a4.w * xv.w;
                acc1 += b4.x * xv.x + b4.y * xv.y + b4.z * xv.z + b4.w * xv.w;
                acc2 += c4.x * xv.x + c4.y * xv.y + c4.z * xv.z + c4.w * xv.w;
            }
            #pragma unroll
            for (int off = 32; off; off >>= 1) {
                acc0 += __shfl_xor(acc0, off);
                acc1 += __shfl_xor(acc1, off);
                acc2 += __shfl_xor(acc2, off);
            }
            if (lane == 0) {
                float gi_r = acc0 + b_ih[j];
                float gi_z = acc1 + b_ih[H + j];
                float gi_n = acc2 + b_ih[2 * H + j];
                float r = 1.f / (1.f + expf(-(gi_r + b_hh[j])));
                float z = 1.f / (1.f + expf(-(gi_z + b_hh[H + j])));
                float n = tanhf(gi_n + r * b_hh[2 * H + j]);
                float hnew = (1.f - z) * n;         // + z*h0, h0 = 0
                float outv = 1.f / (1.f + expf(-hnew));
                d_out[j] = outv;                    // out
                d_out[H + j] = hnew;                // h_new
            }
        }
    }
}

extern "C" void kernel_launch(void* const* d_in, const int* in_sizes, int n_in,
                              void* d_out, int out_size, void* d_ws, size_t ws_size,
                              hipStream_t stream) {
    const int*   inputId     = (const int*)d_in[0];
    const float* hidden      = (const float*)d_in[1];
    const float* enc         = (const float*)d_in[2];
    const float* embed_table = (const float*)d_in[3];
    const float* attn_w      = (const float*)d_in[4];
    const float* attn_b      = (const float*)d_in[5];
    const float* comb_w      = (const float*)d_in[6];
    const float* comb_b      = (const float*)d_in[7];
    const float* w_ih        = (const float*)d_in[8];
    // d_in[9] = w_hh is dead: h0 == 0 so gh = b_hh
    const float* b_ih        = (const float*)d_in[10];
    const float* b_hh        = (const float*)d_in[11];

    float* out = (float*)d_out;   // [0:1024) out, [1024:2048) h_new, [2048:2560) attnWeights
    float* ws  = (float*)d_ws;

    // zero the barrier counters every call (deterministic across graph replays)
    hipMemsetAsync(d_ws, 0, 2048, stream);

    void* args[] = {
        (void*)&inputId, (void*)&hidden, (void*)&enc, (void*)&embed_table,
        (void*)&attn_w, (void*)&attn_b, (void*)&comb_w, (void*)&comb_b,
        (void*)&w_ih, (void*)&b_ih, (void*)&b_hh, (void*)&out, (void*)&ws
    };
    hipLaunchCooperativeKernel((const void*)fused_decoder, dim3(NB), dim3(NT),
                               args, 0, stream);
}